// Round 12
// baseline (401.424 us; speedup 1.0000x reference)
//
#include <hip/hip_runtime.h>
#include <hip/hip_bf16.h>

// LSTMFeatureExtractor: 2-layer LSTM (H=64, IN=1, B=2048, T=512) + FC(64->32)+ReLU
// R16 = two independent blocks/CU. R15 (273us, step 1280cy) budget: MFMA 410 +
// pure VALU ~153 + ~717cy SIMD-idle (serial barrier->ds_read->MFMA->trans->
// write chain; 2 lockstep waves can't hide it; R9/R11-R14 all failed intra-
// block). Mechanism: co-resident blocks have uncorrelated barriers -> block B
// issues through block A's stalls. Cost: MB=4 => 4x M-repl => 48 MFMA/SIMD/
// step (~820cy) -- useful issue that fills the idle. Role-balanced mapping:
// role = (wave>>1) ^ (blockIdx&1) so each SIMD gets one L0-role + one L1-role
// wave (R6/R10 lacked this). Full R15 VALU diet kept: prescaled weights,
// bias/x in MFMA C, fused 7-trans cell, f32x2 packing over the lane's 2 units.
// Tripwires: WRITE_SIZE 256KB (spill), dur>=500us (1 block/CU resident).

#define HID 64
#define TSTEPS 512
#define MB 4
#define RS 80   // f16 row stride: 160B

typedef _Float16 f16x8 __attribute__((ext_vector_type(8)));
typedef float f32x4 __attribute__((ext_vector_type(4)));
typedef float f32x2 __attribute__((ext_vector_type(2)));

#define KSIG (-1.44269504089f)   // -log2(e)
#define KTANH (2.88539008178f)   // 2*log2(e)

__device__ __forceinline__ f32x2 mk2(float a, float b) { f32x2 r; r[0] = a; r[1] = b; return r; }
__device__ __forceinline__ f32x2 exp2v(f32x2 v) {
    f32x2 r; r[0] = __builtin_amdgcn_exp2f(v[0]); r[1] = __builtin_amdgcn_exp2f(v[1]); return r;
}
__device__ __forceinline__ f32x2 rcpv(f32x2 v) {
    f32x2 r; r[0] = __builtin_amdgcn_rcpf(v[0]); r[1] = __builtin_amdgcn_rcpf(v[1]); return r;
}

#define MFMA16(A, B, C) __builtin_amdgcn_mfma_f32_16x16x32_f16((A), (B), (C), 0, 0, 0)

__global__ __launch_bounds__(256, 2) void lstm_feat_kernel(
    const float* __restrict__ x,
    const float* __restrict__ Wih0, const float* __restrict__ Whh0,
    const float* __restrict__ bih0, const float* __restrict__ bhh0,
    const float* __restrict__ Wih1, const float* __restrict__ Whh1,
    const float* __restrict__ bih1, const float* __restrict__ bhh1,
    const float* __restrict__ fcW, const float* __restrict__ fcb,
    float* __restrict__ out)
{
    __shared__ __align__(16) float x_lds[MB * TSTEPS];      // [b][t], 8 KB
    __shared__ __align__(16) _Float16 h0_lds[2][MB * RS];   // ping-pong
    __shared__ __align__(16) _Float16 h1_lds[2][MB * RS];
    __shared__ float h1f32[MB * HID];                       // 1 KB
    __shared__ float fcw_lds[HID * 32];                     // transposed [k][o], 8 KB
    __shared__ float fcb_lds[32];

    const int tid  = threadIdx.x;
    const int wave = tid >> 6;          // 0..3
    const int lane = tid & 63;
    const int nq   = lane & 15;
    const int quad = lane >> 4;
    const int bbase = blockIdx.x * MB;
    // role-balanced: SIMD s hosts one L0-role and one L1-role wave across the
    // two co-resident blocks (parity flip).
    const bool isL1 = ((wave >> 1) ^ (blockIdx.x & 1)) != 0;
    const int U0 = (wave & 1) * 32;     // this wave's 32 units

    // ---- one-time staging ----
    for (int i = tid; i < MB * TSTEPS; i += 256) {
        int r = i >> 9, t = i & (TSTEPS - 1);
        x_lds[r * TSTEPS + t] = x[(bbase + r) * TSTEPS + t];   // coalesced in t
    }
    for (int i = tid; i < 32 * HID; i += 256) {
        int o = i >> 6, kk = i & 63;
        fcw_lds[kk * 32 + o] = fcW[i];
    }
    if (tid < 32) fcb_lds[tid] = fcb[tid];
    for (int i = tid; i < 2 * MB * RS; i += 256) {
        ((_Float16*)h0_lds)[i] = (_Float16)0.f;
        ((_Float16*)h1_lds)[i] = (_Float16)0.f;
    }

    // ---- per-lane tiles: t = hh*4+g, col n = g*64 + U0 + hh*16 + nq ----
    // L0 waves: wA = Whh0 (+ wx0/bs). L1 waves: wA = Wih1, wB = Whh1 (+ cb).
    f16x8 wA[8][2], wB[8][2];
    float bs0[8], wx0[8];               // L0: scaled bias, x-weight
    {
        const float* Wa = isL1 ? Wih1 : Whh0;
        const float* bi = isL1 ? bih1 : bih0;
        const float* bh = isL1 ? bhh1 : bhh0;
        #pragma unroll
        for (int t = 0; t < 8; ++t) {
            const int g = t & 3, hh = t >> 2;
            const int n = g * 64 + U0 + hh * 16 + nq;
            const float sc = (g == 2) ? KTANH : KSIG;
            bs0[t] = (bi[n] + bh[n]) * sc;          // L1 uses as cb
            wx0[t] = Wih0[n] * sc;                  // L0 only (IN==1)
            #pragma unroll
            for (int ks = 0; ks < 2; ++ks) {
                const int k0 = quad * 8 + ks * 32;
                f16x8 a;
                #pragma unroll
                for (int j = 0; j < 8; ++j)
                    a[j] = (_Float16)(Wa[n * HID + k0 + j] * sc);
                wA[t][ks] = a;
            }
        }
        if (isL1) {
            #pragma unroll
            for (int t = 0; t < 8; ++t) {
                const int g = t & 3, hh = t >> 2;
                const int n = g * 64 + U0 + hh * 16 + nq;
                const float sc = (g == 2) ? KTANH : KSIG;
                #pragma unroll
                for (int ks = 0; ks < 2; ++ks) {
                    const int k0 = quad * 8 + ks * 32;
                    f16x8 b;
                    #pragma unroll
                    for (int j = 0; j < 8; ++j)
                        b[j] = (_Float16)(Whh1[n * HID + k0 + j] * sc);
                    wB[t][ks] = b;
                }
            }
        }
    }

    // A row m carries h[m>>2] (4x repl): lane reads A-row nq -> batch nq>>2.
    // D rows quad*4+e all -> batch quad; elems identical -> use [0].
    const int arow = (nq >> 2) * RS + quad * 8;
    const int wad  = quad * RS + U0 + nq;   // h write: unit hh0 (+16 for hh1)
    float cc0 = 0.f, cc1 = 0.f;             // cell state for the unit pair
    f32x2 cc = mk2(cc0, cc1);

    __syncthreads();

// ---- fused cell (7 trans): pre-acts packed over unit pair (hh0, hh1) ----
#define FCELL(PI, PF, PG, PO, HH) do {                                               \
    f32x2 ea = exp2v(PI), eb = exp2v(PF), eg = exp2v(PG), ed = exp2v(PO);            \
    f32x2 Aq = ea + 1.f, Bq = eb + 1.f, Gp = eg + 1.f, Dn = ed + 1.f;                \
    f32x2 AG = Aq * Gp;                                                              \
    f32x2 r1 = rcpv(AG * Bq);                                                        \
    f32x2 nm = cc * AG + (eg - 1.f) * Bq;                                            \
    cc = nm * r1;                                                                    \
    f32x2 E  = exp2v(cc * KTANH);                                                    \
    f32x2 r2 = rcpv(Dn * (E + 1.f));                                                 \
    HH = (E - 1.f) * r2;                                                             \
} while (0)

// ---- L0 substep: H0 buf P + x -> H0 buf Q (16 MFMA: 8 indep 2-chains) ----
#define L0_SUB(P, Q, XS) do {                                                        \
    f16x8 a0 = *(const f16x8*)&h0_lds[P][arow];                                      \
    f16x8 a1 = *(const f16x8*)&h0_lds[P][arow + 32];                                 \
    f32x4 ac[8];                                                                     \
    __builtin_amdgcn_s_setprio(1);                                                   \
    _Pragma("unroll")                                                                \
    for (int t = 0; t < 8; ++t) {                                                    \
        const float cv = fmaf((XS), wx0[t], bs0[t]);                                 \
        f32x4 C = {cv, cv, cv, cv};                                                  \
        ac[t] = MFMA16(a0, wA[t][0], C);                                             \
    }                                                                                \
    _Pragma("unroll")                                                                \
    for (int t = 0; t < 8; ++t) ac[t] = MFMA16(a1, wA[t][1], ac[t]);                 \
    __builtin_amdgcn_s_setprio(0);                                                   \
    f32x2 pi = mk2(ac[0][0], ac[4][0]);                                              \
    f32x2 pf = mk2(ac[1][0], ac[5][0]);                                              \
    f32x2 pg = mk2(ac[2][0], ac[6][0]);                                              \
    f32x2 po = mk2(ac[3][0], ac[7][0]);                                              \
    f32x2 hh;                                                                        \
    FCELL(pi, pf, pg, po, hh);                                                       \
    h0_lds[Q][wad]      = (_Float16)hh[0];                                           \
    h0_lds[Q][wad + 16] = (_Float16)hh[1];                                           \
} while (0)

// ---- L1 substep: H0 buf P + H1 buf P -> H1 buf Q (32 MFMA: 8 x 4-chains) ----
#define L1_SUB(P, Q, GUARD) do {                                                     \
    f16x8 a00 = *(const f16x8*)&h0_lds[P][arow];                                     \
    f16x8 a01 = *(const f16x8*)&h0_lds[P][arow + 32];                                \
    f16x8 a10 = *(const f16x8*)&h1_lds[P][arow];                                     \
    f16x8 a11 = *(const f16x8*)&h1_lds[P][arow + 32];                                \
    f32x4 ac[8];                                                                     \
    __builtin_amdgcn_s_setprio(1);                                                   \
    _Pragma("unroll")                                                                \
    for (int t = 0; t < 8; ++t) {                                                    \
        f32x4 C = {bs0[t], bs0[t], bs0[t], bs0[t]};                                  \
        ac[t] = MFMA16(a00, wA[t][0], C);                                            \
    }                                                                                \
    _Pragma("unroll")                                                                \
    for (int t = 0; t < 8; ++t) ac[t] = MFMA16(a01, wA[t][1], ac[t]);                \
    _Pragma("unroll")                                                                \
    for (int t = 0; t < 8; ++t) ac[t] = MFMA16(a10, wB[t][0], ac[t]);                \
    _Pragma("unroll")                                                                \
    for (int t = 0; t < 8; ++t) ac[t] = MFMA16(a11, wB[t][1], ac[t]);                \
    __builtin_amdgcn_s_setprio(0);                                                   \
    if (GUARD) {                                                                     \
        f32x2 pi = mk2(ac[0][0], ac[4][0]);                                          \
        f32x2 pf = mk2(ac[1][0], ac[5][0]);                                          \
        f32x2 pg = mk2(ac[2][0], ac[6][0]);                                          \
        f32x2 po = mk2(ac[3][0], ac[7][0]);                                          \
        f32x2 hh;                                                                    \
        FCELL(pi, pf, pg, po, hh);                                                   \
        h1_lds[Q][wad]      = (_Float16)hh[0];                                       \
        h1_lds[Q][wad + 16] = (_Float16)hh[1];                                       \
    }                                                                                \
} while (0)

    // ---- skewed recurrence, unrolled x2 (buffers 0->1 then 1->0) ----
    const int xoff = quad * TSTEPS;
    for (int k = 0; k < TSTEPS; k += 2) {
        f32x2 xv;
        if (!isL1) xv = *(const f32x2*)&x_lds[xoff + k];
        if (!isL1) { L0_SUB(0, 1, xv[0]); } else { L1_SUB(0, 1, (k > 0)); }
        __syncthreads();
        if (!isL1) { L0_SUB(1, 0, xv[1]); } else { L1_SUB(1, 0, true); }
        __syncthreads();
    }

    // ---- peeled final L1 step: H1[512] from H0[512] (buf 0), H1[511] (buf 0) ----
    if (isL1) {
        f16x8 a00 = *(const f16x8*)&h0_lds[0][arow];
        f16x8 a01 = *(const f16x8*)&h0_lds[0][arow + 32];
        f16x8 a10 = *(const f16x8*)&h1_lds[0][arow];
        f16x8 a11 = *(const f16x8*)&h1_lds[0][arow + 32];
        f32x4 ac[8];
        #pragma unroll
        for (int t = 0; t < 8; ++t) {
            f32x4 C = {bs0[t], bs0[t], bs0[t], bs0[t]};
            ac[t] = MFMA16(a00, wA[t][0], C);
        }
        #pragma unroll
        for (int t = 0; t < 8; ++t) ac[t] = MFMA16(a01, wA[t][1], ac[t]);
        #pragma unroll
        for (int t = 0; t < 8; ++t) ac[t] = MFMA16(a10, wB[t][0], ac[t]);
        #pragma unroll
        for (int t = 0; t < 8; ++t) ac[t] = MFMA16(a11, wB[t][1], ac[t]);
        f32x2 pi = mk2(ac[0][0], ac[4][0]);
        f32x2 pf = mk2(ac[1][0], ac[5][0]);
        f32x2 pg = mk2(ac[2][0], ac[6][0]);
        f32x2 po = mk2(ac[3][0], ac[7][0]);
        f32x2 hh;
        FCELL(pi, pf, pg, po, hh);
        h1f32[quad * HID + U0 + nq]      = hh[0];
        h1f32[quad * HID + U0 + 16 + nq] = hh[1];
    }
    __syncthreads();

    // ---- epilogue: features = relu(H1[512] @ fcW^T + fcb) ----
    if (tid < MB * 32) {
        const int o  = tid & 31;
        const int rr = tid >> 5;
        float acc = fcb_lds[o];
        #pragma unroll 8
        for (int kk = 0; kk < HID; ++kk)
            acc += h1f32[rr * HID + kk] * fcw_lds[kk * 32 + o];
        out[(bbase + rr) * 32 + o] = fmaxf(acc, 0.f);
    }
}

extern "C" void kernel_launch(void* const* d_in, const int* in_sizes, int n_in,
                              void* d_out, int out_size, void* d_ws, size_t ws_size,
                              hipStream_t stream) {
    const float* x    = (const float*)d_in[0];
    const float* Wih0 = (const float*)d_in[1];
    const float* Whh0 = (const float*)d_in[2];
    const float* bih0 = (const float*)d_in[3];
    const float* bhh0 = (const float*)d_in[4];
    const float* Wih1 = (const float*)d_in[5];
    const float* Whh1 = (const float*)d_in[6];
    const float* bih1 = (const float*)d_in[7];
    const float* bhh1 = (const float*)d_in[8];
    const float* fcW  = (const float*)d_in[9];
    const float* fcb  = (const float*)d_in[10];
    float* out = (float*)d_out;

    lstm_feat_kernel<<<2048 / MB, 256, 0, stream>>>(
        x, Wih0, Whh0, bih0, bhh0, Wih1, Whh1, bih1, bhh1, fcW, fcb, out);
}